// Round 2
// baseline (1362.365 us; speedup 1.0000x reference)
//
#include <hip/hip_runtime.h>
#include <cmath>

#define BATCH 32768
#define LEN   2048
#define NGRP  4
#define GLEN  64

__device__ __forceinline__ float fast_tanh(float x){
    float ax = fabsf(x);
    float e  = __expf(-2.f*ax);
    float r  = __fdividef(1.f - e, 1.f + e);
    return copysignf(r, x);
}
__device__ __forceinline__ float tanh2(float x){ return fast_tanh(fast_tanh(x)); }

// Kernel A: x_site conv + double tanh, fused compact gather of xm while row is L1-hot.
__global__ __launch_bounds__(256) void k_site(
    const float* __restrict__ x, const int* __restrict__ idx,
    const float* __restrict__ v1, const float* __restrict__ g1, const float* __restrict__ b1,
    float* __restrict__ xsite, float* __restrict__ xmws, int use_ws)
{
    float nrm = sqrtf(v1[0]*v1[0] + v1[1]*v1[1] + v1[2]*v1[2]);
    float s  = g1[0]/nrm;
    float w0 = v1[0]*s, w1 = v1[1]*s, w2 = v1[2]*s, bb = b1[0];

    __shared__ int sidx[256];
    sidx[threadIdx.x] = idx[threadIdx.x];
    __syncthreads();

    const int t = threadIdx.x;
    for (int rr = 0; rr < 4; ++rr){
        const int row = blockIdx.x*4 + rr;
        const float* xr  = x     + (size_t)row*LEN;
        float*       orr = xsite + (size_t)row*LEN;
        const int p0 = t*8;
        float4 a = *(const float4*)(xr + p0);
        float4 b = *(const float4*)(xr + p0 + 4);
        if (use_ws)
            xmws[(size_t)row*256 + t] = xr[sidx[t]];  // L1 hit; coalesced write
        float in[10];
        in[0] = (p0 == 0) ? 0.f : xr[p0-1];
        in[1]=a.x; in[2]=a.y; in[3]=a.z; in[4]=a.w;
        in[5]=b.x; in[6]=b.y; in[7]=b.z; in[8]=b.w;
        in[9] = (p0 + 8 >= LEN) ? 0.f : xr[p0+8];
        float o[8];
        #pragma unroll
        for (int c = 0; c < 8; ++c)
            o[c] = tanh2(fmaf(w0, in[c], fmaf(w1, in[c+1], fmaf(w2, in[c+2], bb))));
        *(float4*)(orr + p0)     = make_float4(o[0],o[1],o[2],o[3]);
        *(float4*)(orr + p0 + 4) = make_float4(o[4],o[5],o[6],o[7]);
    }
}

// Kernel B v2: j-split x4.  thread = (row_local rl 0..15, group g 0..3, slice s 0..3)
// Each thread computes 16 of the 64 outputs of its (row,group).
// 8192 waves total (vs 2048) -> latency hiding; LDS exchange for l12 / xmask;
// LDS-staged coalesced output (kills the 4x WRITE_SIZE amplification).
__global__ __launch_bounds__(256, 4) void k_bag(
    const float* __restrict__ x, const float* __restrict__ xmws, const int* __restrict__ idx,
    const float* __restrict__ v2, const float* __restrict__ g2, const float* __restrict__ b2,
    const float* __restrict__ W1, const float* __restrict__ bl1,
    const float* __restrict__ W2, const float* __restrict__ bl2,
    const float* __restrict__ Wa, const float* __restrict__ ba,
    float* __restrict__ xbag, int use_ws)
{
    const int t  = threadIdx.x;
    const int s  = t & 3;               // j-slice
    const int g  = (t >> 2) & 3;        // group
    const int rl = t >> 4;              // 0..15 local row
    const int row = blockIdx.x*16 + rl;
    const int rg  = (rl << 2) | g;      // 0..63
    const int j0  = s << 4;             // 0,16,32,48

    // stride 65 words: bank = (rg + j) % 32 -> conflict-free / 2-way everywhere
    __shared__ float b1s[64*65];        // l12 exchange, later x_bag staging
    __shared__ float b2s[64*65];        // xmask exchange

    // ---- load full xm[64] for (row, g); registers, statically indexed only
    float xm[GLEN];
    if (use_ws){
        const float4* p = (const float4*)(xmws + (size_t)row*256 + (g << 6));
        #pragma unroll
        for (int q = 0; q < 16; ++q){
            float4 v = p[q];
            xm[4*q+0]=v.x; xm[4*q+1]=v.y; xm[4*q+2]=v.z; xm[4*q+3]=v.w;
        }
    } else {
        const float* xr = x + (size_t)row*LEN;
        #pragma unroll
        for (int k = 0; k < GLEN; ++k) xm[k] = xr[idx[(g << 6) + k]];
    }

    // ---- Phase A: own 16-j slice of l12 = relu(xm@W1^T)+relu(xm@W2^T) -> LDS
    {
        const float4* W1v = (const float4*)W1;
        const float4* W2v = (const float4*)W2;
        float* Lw = b1s + rg*65 + j0;
        #pragma unroll 2
        for (int jj = 0; jj < 16; ++jj){
            const int j = j0 + jj;
            float a1 = bl1[j], a2 = bl2[j];
            #pragma unroll
            for (int q = 0; q < 16; ++q){
                float4 u = W1v[j*16 + q];
                float4 w = W2v[j*16 + q];
                a1 = fmaf(xm[4*q+0],u.x, fmaf(xm[4*q+1],u.y, fmaf(xm[4*q+2],u.z, fmaf(xm[4*q+3],u.w, a1))));
                a2 = fmaf(xm[4*q+0],w.x, fmaf(xm[4*q+1],w.y, fmaf(xm[4*q+2],w.z, fmaf(xm[4*q+3],w.w, a2))));
            }
            Lw[jj] = fmaxf(a1, 0.f) + fmaxf(a2, 0.f);
        }
    }
    __syncthreads();

    // ---- Phase B: acc[16] = (full l12 from LDS) @ Wa^T slice
    float acc[16];
    #pragma unroll
    for (int jj = 0; jj < 16; ++jj) acc[jj] = ba[j0 + jj];
    {
        const float4* Wav = (const float4*)Wa;
        const float* Lr = b1s + rg*65;
        #pragma unroll 2
        for (int q = 0; q < 16; ++q){
            const float l0 = Lr[4*q+0], l1 = Lr[4*q+1], l2 = Lr[4*q+2], l3 = Lr[4*q+3];
            #pragma unroll
            for (int jj = 0; jj < 16; ++jj){
                float4 u = Wav[(j0+jj)*16 + q];
                acc[jj] = fmaf(l0,u.x, fmaf(l1,u.y, fmaf(l2,u.z, fmaf(l3,u.w, acc[jj]))));
            }
        }
    }

    // ---- Phase C: A = sigmoid(acc); xmask = (A+1)*xm  -> LDS (slice only)
    {
        float xs[16];   // reload own slice: avoids runtime-indexing xm[] (scratch hazard)
        if (use_ws){
            const float4* p = (const float4*)(xmws + (size_t)row*256 + (g << 6) + j0);
            #pragma unroll
            for (int c = 0; c < 4; ++c){
                float4 v = p[c];
                xs[4*c+0]=v.x; xs[4*c+1]=v.y; xs[4*c+2]=v.z; xs[4*c+3]=v.w;
            }
        } else {
            const float* xr = x + (size_t)row*LEN;
            #pragma unroll
            for (int k = 0; k < 16; ++k) xs[k] = xr[idx[(g << 6) + j0 + k]];
        }
        float* Xw = b2s + rg*65 + j0;
        #pragma unroll
        for (int jj = 0; jj < 16; ++jj){
            float A = __fdividef(1.f, 1.f + __expf(-acc[jj]));
            Xw[jj] = (A + 1.f) * xs[jj];
        }
    }
    __syncthreads();

    // ---- Phase D: 4-channel conv(k=3) over own slice + tanh2 -> stage in b1s
    {
        float nn = 0.f;
        #pragma unroll
        for (int i = 0; i < NGRP; ++i)
            #pragma unroll
            for (int d = 0; d < 3; ++d){ float tv = v2[(g*NGRP + i)*3 + d]; nn += tv*tv; }
        const float sc = g2[g] / sqrtf(nn);

        float o[16];
        const float bo = b2[g];
        #pragma unroll
        for (int jj = 0; jj < 16; ++jj) o[jj] = bo;

        #pragma unroll
        for (int i = 0; i < NGRP; ++i){
            const float w0 = v2[(g*NGRP + i)*3 + 0] * sc;
            const float w1 = v2[(g*NGRP + i)*3 + 1] * sc;
            const float w2 = v2[(g*NGRP + i)*3 + 2] * sc;
            const float* c = b2s + (((rl << 2) | i))*65 + j0;
            float xp = (s == 0) ? 0.f : c[-1];
            float xc = c[0];
            #pragma unroll
            for (int jj = 0; jj < 16; ++jj){
                float xn = (jj < 15) ? c[jj+1] : ((s == 3) ? 0.f : c[16]);
                o[jj] = fmaf(w0, xp, fmaf(w1, xc, fmaf(w2, xn, o[jj])));
                xp = xc; xc = xn;
            }
        }
        float* Ow = b1s + rg*65 + j0;
        #pragma unroll
        for (int jj = 0; jj < 16; ++jj) Ow[jj] = tanh2(o[jj]);
    }
    __syncthreads();

    // ---- coalesced output: 4096 floats/block, full 64B lines per store
    {
        float* ob = xbag + (size_t)blockIdx.x * 4096;
        const int r  = t >> 2;           // = (t*16)>>6, constant per thread
        const int cb = (t & 3) << 4;     // 0,16,32,48
        const float* Or = b1s + r*65 + cb;
        #pragma unroll
        for (int c = 0; c < 4; ++c){
            float4 v = make_float4(Or[4*c+0], Or[4*c+1], Or[4*c+2], Or[4*c+3]);
            *(float4*)(ob + t*16 + 4*c) = v;
        }
    }
}

extern "C" void kernel_launch(void* const* d_in, const int* in_sizes, int n_in,
                              void* d_out, int out_size, void* d_ws, size_t ws_size,
                              hipStream_t stream) {
    const float* x   = (const float*)d_in[0];
    const int*   idx = (const int*)  d_in[1];
    const float* v1  = (const float*)d_in[2];
    const float* g1  = (const float*)d_in[3];
    const float* b1  = (const float*)d_in[4];
    const float* v2  = (const float*)d_in[5];
    const float* g2  = (const float*)d_in[6];
    const float* b2  = (const float*)d_in[7];
    const float* W1  = (const float*)d_in[8];
    const float* bl1 = (const float*)d_in[9];
    const float* W2  = (const float*)d_in[10];
    const float* bl2 = (const float*)d_in[11];
    const float* Wa  = (const float*)d_in[12];
    const float* ba  = (const float*)d_in[13];

    float* xbag  = (float*)d_out;                           // (B, 4, 64)
    float* xsite = (float*)d_out + (size_t)BATCH*NGRP*GLEN; // (B, 1, 2048)
    float* xmws  = (float*)d_ws;
    const int use_ws = (ws_size >= (size_t)BATCH*256*sizeof(float)) ? 1 : 0;

    k_site<<<BATCH/4, 256, 0, stream>>>(x, idx, v1, g1, b1, xsite, xmws, use_ws);
    k_bag <<<BATCH/16, 256, 0, stream>>>(x, xmws, idx, v2, g2, b2,
                                         W1, bl1, W2, bl2, Wa, ba, xbag, use_ws);
}

// Round 3
// 873.351 us; speedup vs baseline: 1.5599x; 1.5599x over previous
//
#include <hip/hip_runtime.h>
#include <cmath>

#define BATCH 32768
#define LEN   2048
#define NGRP  4
#define GLEN  64

__device__ __forceinline__ float fast_tanh(float x){
    float ax = fabsf(x);
    float e  = __expf(-2.f*ax);
    float r  = __fdividef(1.f - e, 1.f + e);
    return copysignf(r, x);
}
__device__ __forceinline__ float tanh2(float x){ return fast_tanh(fast_tanh(x)); }

// Kernel A: x_site conv + double tanh, fused compact gather of xm while row is L1-hot.
// (unchanged from the 237/710 baseline for attribution)
__global__ __launch_bounds__(256) void k_site(
    const float* __restrict__ x, const int* __restrict__ idx,
    const float* __restrict__ v1, const float* __restrict__ g1, const float* __restrict__ b1,
    float* __restrict__ xsite, float* __restrict__ xmws, int use_ws)
{
    float nrm = sqrtf(v1[0]*v1[0] + v1[1]*v1[1] + v1[2]*v1[2]);
    float s  = g1[0]/nrm;
    float w0 = v1[0]*s, w1 = v1[1]*s, w2 = v1[2]*s, bb = b1[0];

    __shared__ int sidx[256];
    sidx[threadIdx.x] = idx[threadIdx.x];
    __syncthreads();

    const int t = threadIdx.x;
    for (int rr = 0; rr < 4; ++rr){
        const int row = blockIdx.x*4 + rr;
        const float* xr  = x     + (size_t)row*LEN;
        float*       orr = xsite + (size_t)row*LEN;
        const int p0 = t*8;
        float4 a = *(const float4*)(xr + p0);
        float4 b = *(const float4*)(xr + p0 + 4);
        if (use_ws)
            xmws[(size_t)row*256 + t] = xr[sidx[t]];  // L1 hit; coalesced write
        float in[10];
        in[0] = (p0 == 0) ? 0.f : xr[p0-1];
        in[1]=a.x; in[2]=a.y; in[3]=a.z; in[4]=a.w;
        in[5]=b.x; in[6]=b.y; in[7]=b.z; in[8]=b.w;
        in[9] = (p0 + 8 >= LEN) ? 0.f : xr[p0+8];
        float o[8];
        #pragma unroll
        for (int c = 0; c < 8; ++c)
            o[c] = tanh2(fmaf(w0, in[c], fmaf(w1, in[c+1], fmaf(w2, in[c+2], bb))));
        *(float4*)(orr + p0)     = make_float4(o[0],o[1],o[2],o[3]);
        *(float4*)(orr + p0 + 4) = make_float4(o[4],o[5],o[6],o[7]);
    }
}

// Kernel B v3: K-SPLIT x4. thread = (rl 0..15, g 0..3, s 0..3); s owns k-slice [16s,16s+16).
// Partial dot products reduced across the 4 s-lanes with __shfl_xor(1),(2).
// Thread's kept j-slice == its k-slice == its xm slice -> no LDS for l12/xm,
// registers never exceed ~50 floats of arrays -> NO SPILL (v1/v2 both spilled).
// One LDS buffer (xmask exchange for the cross-group conv), one barrier.
__global__ __launch_bounds__(256, 4) void k_bag(
    const float* __restrict__ x, const float* __restrict__ xmws, const int* __restrict__ idx,
    const float* __restrict__ v2, const float* __restrict__ g2, const float* __restrict__ b2,
    const float* __restrict__ W1, const float* __restrict__ bl1,
    const float* __restrict__ W2, const float* __restrict__ bl2,
    const float* __restrict__ Wa, const float* __restrict__ ba,
    float* __restrict__ xbag, int use_ws)
{
    const int t  = threadIdx.x;
    const int s  = t & 3;               // k-slice / j-slice owner
    const int g  = (t >> 2) & 3;        // group
    const int rl = t >> 4;              // 0..15 local row
    const int row = blockIdx.x*16 + rl;
    const int rg  = (rl << 2) | g;      // 0..63
    const int k0  = s << 4;             // slice base

    // xmask exchange. stride 65 words -> conv reads are 2-way banked (free, m136).
    __shared__ float X[64*65];

    // ---- load xm k-slice (16 floats, 64B contiguous per lane -> coalesced)
    float xm[16];
    if (use_ws){
        const float4* p = (const float4*)(xmws + (size_t)row*256 + (g << 6) + k0);
        #pragma unroll
        for (int q = 0; q < 4; ++q){
            float4 v = p[q];
            xm[4*q+0]=v.x; xm[4*q+1]=v.y; xm[4*q+2]=v.z; xm[4*q+3]=v.w;
        }
    } else {
        const float* xr = x + (size_t)row*LEN;
        #pragma unroll
        for (int k = 0; k < 16; ++k) xm[k] = xr[idx[(g << 6) + k0 + k]];
    }

    // ---- Phase A: l12[jj] for own j-slice; every j reduced across s-lanes
    float l12[16];
    {
        const float4* W1v = (const float4*)W1;
        const float4* W2v = (const float4*)W2;
        #pragma unroll
        for (int jj = 0; jj < 16; ++jj){
            #pragma unroll
            for (int ss = 0; ss < 4; ++ss){
                const int j = (ss << 4) + jj;
                float a1 = 0.f, a2 = 0.f;
                #pragma unroll
                for (int q = 0; q < 4; ++q){
                    float4 u = W1v[j*16 + s*4 + q];
                    float4 w = W2v[j*16 + s*4 + q];
                    a1 = fmaf(xm[4*q+0],u.x, fmaf(xm[4*q+1],u.y, fmaf(xm[4*q+2],u.z, fmaf(xm[4*q+3],u.w, a1))));
                    a2 = fmaf(xm[4*q+0],w.x, fmaf(xm[4*q+1],w.y, fmaf(xm[4*q+2],w.z, fmaf(xm[4*q+3],w.w, a2))));
                }
                a1 += __shfl_xor(a1, 1); a1 += __shfl_xor(a1, 2);
                a2 += __shfl_xor(a2, 1); a2 += __shfl_xor(a2, 2);
                if (s == ss)
                    l12[jj] = fmaxf(a1 + bl1[j], 0.f) + fmaxf(a2 + bl2[j], 0.f);
            }
        }
    }

    // ---- Phase B+C fused: gate GEMV (k-split over l12) + sigmoid + mask.
    // Own j-slice of the gate == own xm slice -> xmask from registers.
    float xk[16];
    {
        const float4* Wav = (const float4*)Wa;
        #pragma unroll
        for (int jj = 0; jj < 16; ++jj){
            #pragma unroll
            for (int ss = 0; ss < 4; ++ss){
                const int j = (ss << 4) + jj;
                float a = 0.f;
                #pragma unroll
                for (int q = 0; q < 4; ++q){
                    float4 u = Wav[j*16 + s*4 + q];
                    a = fmaf(l12[4*q+0],u.x, fmaf(l12[4*q+1],u.y, fmaf(l12[4*q+2],u.z, fmaf(l12[4*q+3],u.w, a))));
                }
                a += __shfl_xor(a, 1); a += __shfl_xor(a, 2);
                if (s == ss){
                    float A = __fdividef(1.f, 1.f + __expf(-(a + ba[j])));
                    xk[jj] = (A + 1.f) * xm[jj];
                }
            }
        }
    }
    {
        float* Xw = X + rg*65 + k0;
        #pragma unroll
        for (int jj = 0; jj < 16; ++jj) Xw[jj] = xk[jj];
    }
    __syncthreads();

    // ---- Phase D: 4-channel conv(k=3) over own j-slice + tanh2 -> direct store
    {
        float nn = 0.f;
        #pragma unroll
        for (int i = 0; i < NGRP; ++i)
            #pragma unroll
            for (int d = 0; d < 3; ++d){ float tv = v2[(g*NGRP + i)*3 + d]; nn += tv*tv; }
        const float sc = g2[g] / sqrtf(nn);

        float o[16];
        const float bo = b2[g];
        #pragma unroll
        for (int jj = 0; jj < 16; ++jj) o[jj] = bo;

        #pragma unroll
        for (int i = 0; i < NGRP; ++i){
            const float w0 = v2[(g*NGRP + i)*3 + 0] * sc;
            const float w1 = v2[(g*NGRP + i)*3 + 1] * sc;
            const float w2 = v2[(g*NGRP + i)*3 + 2] * sc;
            const float* c = X + (((rl << 2) | i))*65 + k0;
            float xp = (s == 0) ? 0.f : c[-1];
            float xc = c[0];
            #pragma unroll
            for (int jj = 0; jj < 16; ++jj){
                float xn = (jj < 15) ? c[jj+1] : ((s == 3) ? 0.f : c[16]);
                o[jj] = fmaf(w0, xp, fmaf(w1, xc, fmaf(w2, xn, o[jj])));
                xp = xc; xc = xn;
            }
        }

        // each lane owns 64B of output -> 4 float4 stores, lines fully covered per wave
        float* ob = xbag + (size_t)row*(NGRP*GLEN) + (g << 6) + k0;
        #pragma unroll
        for (int q = 0; q < 4; ++q){
            *(float4*)(ob + 4*q) = make_float4(tanh2(o[4*q+0]), tanh2(o[4*q+1]),
                                               tanh2(o[4*q+2]), tanh2(o[4*q+3]));
        }
    }
}

extern "C" void kernel_launch(void* const* d_in, const int* in_sizes, int n_in,
                              void* d_out, int out_size, void* d_ws, size_t ws_size,
                              hipStream_t stream) {
    const float* x   = (const float*)d_in[0];
    const int*   idx = (const int*)  d_in[1];
    const float* v1  = (const float*)d_in[2];
    const float* g1  = (const float*)d_in[3];
    const float* b1  = (const float*)d_in[4];
    const float* v2  = (const float*)d_in[5];
    const float* g2  = (const float*)d_in[6];
    const float* b2  = (const float*)d_in[7];
    const float* W1  = (const float*)d_in[8];
    const float* bl1 = (const float*)d_in[9];
    const float* W2  = (const float*)d_in[10];
    const float* bl2 = (const float*)d_in[11];
    const float* Wa  = (const float*)d_in[12];
    const float* ba  = (const float*)d_in[13];

    float* xbag  = (float*)d_out;                           // (B, 4, 64)
    float* xsite = (float*)d_out + (size_t)BATCH*NGRP*GLEN; // (B, 1, 2048)
    float* xmws  = (float*)d_ws;
    const int use_ws = (ws_size >= (size_t)BATCH*256*sizeof(float)) ? 1 : 0;

    k_site<<<BATCH/4, 256, 0, stream>>>(x, idx, v1, g1, b1, xsite, xmws, use_ws);
    k_bag <<<BATCH/16, 256, 0, stream>>>(x, xmws, idx, v2, g2, b2,
                                         W1, bl1, W2, bl2, Wa, ba, xbag, use_ws);
}

// Round 4
// 687.096 us; speedup vs baseline: 1.9828x; 1.2711x over previous
//
#include <hip/hip_runtime.h>
#include <cmath>

#define BATCH 32768
#define LEN   2048
#define NGRP  4
#define GLEN  64

__device__ __forceinline__ float fast_tanh(float x){
    float ax = fabsf(x);
    float e  = __expf(-2.f*ax);
    float r  = __fdividef(1.f - e, 1.f + e);
    return copysignf(r, x);
}
__device__ __forceinline__ float tanh2(float x){ return fast_tanh(fast_tanh(x)); }

// Kernel A: x_site conv + double tanh, fused compact gather of xm while row is L1-hot.
// (unchanged from baseline for attribution)
__global__ __launch_bounds__(256) void k_site(
    const float* __restrict__ x, const int* __restrict__ idx,
    const float* __restrict__ v1, const float* __restrict__ g1, const float* __restrict__ b1,
    float* __restrict__ xsite, float* __restrict__ xmws, int use_ws)
{
    float nrm = sqrtf(v1[0]*v1[0] + v1[1]*v1[1] + v1[2]*v1[2]);
    float s  = g1[0]/nrm;
    float w0 = v1[0]*s, w1 = v1[1]*s, w2 = v1[2]*s, bb = b1[0];

    __shared__ int sidx[256];
    sidx[threadIdx.x] = idx[threadIdx.x];
    __syncthreads();

    const int t = threadIdx.x;
    for (int rr = 0; rr < 4; ++rr){
        const int row = blockIdx.x*4 + rr;
        const float* xr  = x     + (size_t)row*LEN;
        float*       orr = xsite + (size_t)row*LEN;
        const int p0 = t*8;
        float4 a = *(const float4*)(xr + p0);
        float4 b = *(const float4*)(xr + p0 + 4);
        if (use_ws)
            xmws[(size_t)row*256 + t] = xr[sidx[t]];  // L1 hit; coalesced write
        float in[10];
        in[0] = (p0 == 0) ? 0.f : xr[p0-1];
        in[1]=a.x; in[2]=a.y; in[3]=a.z; in[4]=a.w;
        in[5]=b.x; in[6]=b.y; in[7]=b.z; in[8]=b.w;
        in[9] = (p0 + 8 >= LEN) ? 0.f : xr[p0+8];
        float o[8];
        #pragma unroll
        for (int c = 0; c < 8; ++c)
            o[c] = tanh2(fmaf(w0, in[c], fmaf(w1, in[c+1], fmaf(w2, in[c+2], bb))));
        *(float4*)(orr + p0)     = make_float4(o[0],o[1],o[2],o[3]);
        *(float4*)(orr + p0 + 4) = make_float4(o[4],o[5],o[6],o[7]);
    }
}

// Kernel B v4: thread per (row,group), scalar-broadcast (wave-uniform s_load) weights.
// EVERY loop that indexes a register array is FULLY unrolled -> all indices compile-time
// -> arrays stay in VGPRs (v1/v2's scratch spill came from `#pragma unroll 2` leaving
// runtime indices, rule #20). acc[64] eliminated by fusing gate->sigmoid->mask per j.
// launch_bounds(128,2) pins the VGPR cap at 256; peak live ~160 floats.
__global__ __launch_bounds__(128, 2) void k_bag(
    const float* __restrict__ x, const float* __restrict__ xmws, const int* __restrict__ idx,
    const float* __restrict__ v2, const float* __restrict__ g2, const float* __restrict__ b2,
    const float* __restrict__ W1, const float* __restrict__ bl1,
    const float* __restrict__ W2, const float* __restrict__ bl2,
    const float* __restrict__ Wa, const float* __restrict__ ba,
    float* __restrict__ xbag, int use_ws)
{
    const int lane = threadIdx.x & 63;
    const int wave = threadIdx.x >> 6;
    const int rl   = lane >> 2;     // 0..15 local row
    const int g    = lane & 3;      // group
    const int row  = blockIdx.x*32 + wave*16 + rl;

    // ---- xm[64] in registers (all further indexing is compile-time)
    float xm[GLEN];
    if (use_ws){
        const float4* p = (const float4*)(xmws + (size_t)row*256 + (g << 6));
        #pragma unroll
        for (int q = 0; q < 16; ++q){
            float4 v = p[q];
            xm[4*q+0]=v.x; xm[4*q+1]=v.y; xm[4*q+2]=v.z; xm[4*q+3]=v.w;
        }
    } else {
        const float* xr = x + (size_t)row*LEN;
        #pragma unroll
        for (int k = 0; k < GLEN; ++k) xm[k] = xr[idx[(g << 6) + k]];
    }

    // ---- Phase A: l12 = relu(xm@W1^T + bl1) + relu(xm@W2^T + bl2); FULL unroll
    float l12[GLEN];
    {
        const float4* W1v = (const float4*)W1;
        const float4* W2v = (const float4*)W2;
        #pragma unroll
        for (int j = 0; j < GLEN; ++j){
            float a1 = bl1[j], a2 = bl2[j];
            #pragma unroll
            for (int q = 0; q < 16; ++q){
                float4 u = W1v[j*16 + q];   // uniform addr -> s_load, SGPR operands
                float4 w = W2v[j*16 + q];
                a1 = fmaf(xm[4*q+0],u.x, fmaf(xm[4*q+1],u.y, fmaf(xm[4*q+2],u.z, fmaf(xm[4*q+3],u.w, a1))));
                a2 = fmaf(xm[4*q+0],w.x, fmaf(xm[4*q+1],w.y, fmaf(xm[4*q+2],w.z, fmaf(xm[4*q+3],w.w, a2))));
            }
            l12[j] = fmaxf(a1, 0.f) + fmaxf(a2, 0.f);
        }
    }

    // ---- Phase B: gate j fused: a -> sigmoid -> xmask -> LDS (no acc[64] array)
    // LDS layout [wave][rl][g*65 + j], row stride 260 words:
    // write bank = (4rl + g + j) % 32 -> 2-way (free); conv read = broadcast across g, 2-way across rl.
    __shared__ float X[2*16*260];
    {
        float* Xw = X + wave*(16*260) + rl*260 + g*65;
        const float4* Wav = (const float4*)Wa;
        #pragma unroll
        for (int j = 0; j < GLEN; ++j){
            float a = ba[j];
            #pragma unroll
            for (int q = 0; q < 16; ++q){
                float4 u = Wav[j*16 + q];
                a = fmaf(l12[4*q+0],u.x, fmaf(l12[4*q+1],u.y, fmaf(l12[4*q+2],u.z, fmaf(l12[4*q+3],u.w, a))));
            }
            float A = __fdividef(1.f, 1.f + __expf(-a));
            Xw[j] = (A + 1.f) * xm[j];
        }
    }
    __syncthreads();

    // ---- Phase C: 4-channel conv(k=3), j-outer / i-inner with rolling regs; no out[64].
    {
        float nn = 0.f;
        #pragma unroll
        for (int i = 0; i < NGRP; ++i)
            #pragma unroll
            for (int d = 0; d < 3; ++d){ float tv = v2[(g*NGRP + i)*3 + d]; nn += tv*tv; }
        const float sc = g2[g] / sqrtf(nn);
        float wv[NGRP][3];
        #pragma unroll
        for (int i = 0; i < NGRP; ++i)
            #pragma unroll
            for (int d = 0; d < 3; ++d) wv[i][d] = v2[(g*NGRP + i)*3 + d] * sc;

        const float* Xr = X + wave*(16*260) + rl*260;
        const float bo = b2[g];
        float xp[NGRP], xc[NGRP];
        #pragma unroll
        for (int i = 0; i < NGRP; ++i){ xp[i] = 0.f; xc[i] = Xr[i*65]; }

        float* ob = xbag + (size_t)row*(NGRP*GLEN) + (g << 6);
        float o4[4];
        #pragma unroll
        for (int j = 0; j < GLEN; ++j){
            float o = bo;
            #pragma unroll
            for (int i = 0; i < NGRP; ++i){
                float xn = (j < GLEN-1) ? Xr[i*65 + j + 1] : 0.f;
                o = fmaf(wv[i][0], xp[i], fmaf(wv[i][1], xc[i], fmaf(wv[i][2], xn, o)));
                xp[i] = xc[i]; xc[i] = xn;
            }
            o4[j & 3] = tanh2(o);
            if ((j & 3) == 3)
                *(float4*)(ob + (j & ~3)) = make_float4(o4[0], o4[1], o4[2], o4[3]);
        }
    }
}

extern "C" void kernel_launch(void* const* d_in, const int* in_sizes, int n_in,
                              void* d_out, int out_size, void* d_ws, size_t ws_size,
                              hipStream_t stream) {
    const float* x   = (const float*)d_in[0];
    const int*   idx = (const int*)  d_in[1];
    const float* v1  = (const float*)d_in[2];
    const float* g1  = (const float*)d_in[3];
    const float* b1  = (const float*)d_in[4];
    const float* v2  = (const float*)d_in[5];
    const float* g2  = (const float*)d_in[6];
    const float* b2  = (const float*)d_in[7];
    const float* W1  = (const float*)d_in[8];
    const float* bl1 = (const float*)d_in[9];
    const float* W2  = (const float*)d_in[10];
    const float* bl2 = (const float*)d_in[11];
    const float* Wa  = (const float*)d_in[12];
    const float* ba  = (const float*)d_in[13];

    float* xbag  = (float*)d_out;                           // (B, 4, 64)
    float* xsite = (float*)d_out + (size_t)BATCH*NGRP*GLEN; // (B, 1, 2048)
    float* xmws  = (float*)d_ws;
    const int use_ws = (ws_size >= (size_t)BATCH*256*sizeof(float)) ? 1 : 0;

    k_site<<<BATCH/4, 256, 0, stream>>>(x, idx, v1, g1, b1, xsite, xmws, use_ws);
    k_bag <<<BATCH/32, 128, 0, stream>>>(x, xmws, idx, v2, g2, b2,
                                         W1, bl1, W2, bl2, Wa, ba, xbag, use_ws);
}